// Round 7
// baseline (507.737 us; speedup 1.0000x reference)
//
#include <hip/hip_runtime.h>
#include <hip/hip_bf16.h>
#include <stdint.h>

typedef unsigned short u16;
typedef __attribute__((ext_vector_type(8))) short bf16x8;
typedef __attribute__((ext_vector_type(4))) float floatx4;

__device__ __forceinline__ float bf2f(u16 v){ return __uint_as_float(((unsigned)v)<<16); }
__device__ __forceinline__ u16 f2bf(float f){
  unsigned u = __float_as_uint(f);
  unsigned r = 0x7fffu + ((u>>16)&1u);
  return (u16)((u+r)>>16);
}
__device__ __forceinline__ float lrelu(float x){ return x > 0.f ? x : 0.2f*x; }
__device__ __forceinline__ float sigm(float t){
  t = fminf(fmaxf(t, -30.f), 30.f);
  return 1.f/(1.f + __expf(-t));
}

#define GLOAD16(ldsdst, gsrc) \
  __builtin_amdgcn_global_load_lds((const __attribute__((address_space(1))) void*)(gsrc), \
      (__attribute__((address_space(3))) void*)(ldsdst), 16, 0, 0)

// ---------------------------------------------------------------------------
// dtype detector: flags[0]=1 -> float inputs are f32; flags[1]=1 -> node_type int64
// ---------------------------------------------------------------------------
__global__ void k_detect(const u16* __restrict__ nodes_raw,
                         const int* __restrict__ ntype_raw, int* flags)
{
  __shared__ int s_wild, s_nz;
  if (threadIdx.x == 0){ s_wild = 0; s_nz = 0; }
  __syncthreads();
  int wild = 0;
#pragma unroll
  for (int i = 0; i < 16; i++){
    u16 w = nodes_raw[threadIdx.x*16 + i];
    int e = (w >> 7) & 0xFF;
    if (e != 0 && (e < 102 || e > 152)) wild++;
  }
  int nz = 0;
  if (threadIdx.x < 255 && ntype_raw[2*threadIdx.x + 1] != 0) nz = 1;
  atomicAdd(&s_wild, wild);
  atomicAdd(&s_nz, nz);
  __syncthreads();
  if (threadIdx.x == 0){
    flags[0] = (s_wild > 1024) ? 1 : 0;
    flags[1] = (s_nz == 0) ? 1 : 0;
  }
}

// --- merged canonicalization of all 13 float tensors (+ nodes into X) ------
struct CanonDesc {
  const void* src[13];
  u16*        dst[13];
  int startBlk[13];
  int n4[13];
};
__global__ __launch_bounds__(256)
void k_canon_all(CanonDesc d, u16* __restrict__ X, const int* __restrict__ flags)
{
  int blk = blockIdx.x;
  int seg = 0;
#pragma unroll
  for (int s = 1; s < 13; s++) if (blk >= d.startBlk[s]) seg = s;
  int i = (blk - d.startBlk[seg])*256 + threadIdx.x;
  if (i >= d.n4[seg]) return;
  uint2 bits;
  if (flags[0]) {
    float4 v = ((const float4*)d.src[seg])[i];
    ushort4 o2;
    o2.x = f2bf(v.x); o2.y = f2bf(v.y); o2.z = f2bf(v.z); o2.w = f2bf(v.w);
    bits = *(uint2*)&o2;
  } else {
    bits = ((const uint2*)d.src[seg])[i];
  }
  ((uint2*)d.dst[seg])[i] = bits;
  if (seg == 0) {               // nodes also -> X[:,0:512), ld 2048
    int e0 = i*4;
    long r = e0 >> 9;
    int  c = e0 & 511;
    *(uint2*)&X[r*2048 + c] = bits;
  }
}

// --- per-type row index lists ----------------------------------------------
__global__ void k_build_idx(const int* __restrict__ ntype, const int* __restrict__ flags,
                            int* __restrict__ idx, int* __restrict__ cnt)
{
  __shared__ int c[3];
  if (threadIdx.x < 3) c[threadIdx.x] = 0;
  __syncthreads();
  const int i64 = flags[1];
  for (int i = threadIdx.x; i < 8192; i += 256){
    int t = i64 ? ntype[2*i] : ntype[i];
    if (t >= 2 && t <= 4){
      int p = atomicAdd(&c[t-2], 1);
      idx[(t-2)*8192 + p] = i;
    }
  }
  __syncthreads();
  if (threadIdx.x < 3) cnt[threadIdx.x] = c[threadIdx.x];
}

// ---------------------------------------------------------------------------
// Wave-block GEMM: 64-thread block = 1 wave computing 64 x (NT*16) tile.
// Barrier-free 3-stage LDS ring; s_waitcnt vmcnt(LD) retires oldest stage
// while 2 younger stages stay in flight. Ring-of-3 gives a full iteration
// of slack between last ds_read of a buffer and its DMA overwrite.
// MODE 0: bm=bx, bn=by, bz=bzi.   MODE 1: bz=bx, bn=by, bm=bzi.
// ---------------------------------------------------------------------------
template<int MODE, int NT, class Epi>
__global__ __launch_bounds__(64, 2)
void gemm_w64(const u16* __restrict__ A, int ldA, long sAz,
              const u16* __restrict__ B, int ldB, long sBz,
              int K, Epi epi)
{
  __shared__ __align__(16) u16 As[3][64][32];
  __shared__ __align__(16) u16 Bs[3][NT*16][32];
  int bm, bn, bz;
  if (MODE == 0){ bm = blockIdx.x; bn = blockIdx.y; bz = blockIdx.z; }
  else          { bz = blockIdx.x; bn = blockIdx.y; bm = blockIdx.z; }
  const int lane = threadIdx.x;
  const int mrow = lane & 15;
  const int quad = lane >> 4;
  const int srow = lane >> 2;          // 0..15
  const int scol = (lane & 3) << 3;    // 8 bf16 = 16B

  const u16* gA[4];
  const u16* gB[NT];
#pragma unroll
  for (int i=0;i<4;i++)
    gA[i] = A + bz*sAz + (long)(bm*64 + i*16 + srow)*ldA + scol;
#pragma unroll
  for (int i=0;i<NT;i++)
    gB[i] = B + bz*sBz + (long)(bn*NT*16 + i*16 + srow)*ldB + scol;

  floatx4 acc[4][NT];
#pragma unroll
  for (int i=0;i<4;i++)
#pragma unroll
    for (int j=0;j<NT;j++) acc[i][j] = 0.f;

  auto issue = [&](int s){
#pragma unroll
    for (int i=0;i<4;i++){ GLOAD16(&As[s][i*16+srow][scol], gA[i]); gA[i] += 32; }
#pragma unroll
    for (int i=0;i<NT;i++){ GLOAD16(&Bs[s][i*16+srow][scol], gB[i]); gB[i] += 32; }
  };

  const int nIter = K >> 5;            // >= 16 at all call sites
  issue(0); issue(1);
  for (int it = 0; it < nIter; ++it) {
    if (it < nIter-1) {
      if (NT == 8) asm volatile("s_waitcnt vmcnt(12)" ::: "memory");
      else         asm volatile("s_waitcnt vmcnt(8)"  ::: "memory");
    } else {
      asm volatile("s_waitcnt vmcnt(0)" ::: "memory");
    }
    const int s = it % 3;
    bf16x8 af[4], bfr[NT];
#pragma unroll
    for (int i=0;i<4;i++)  af[i]  = *(const bf16x8*)&As[s][i*16 + mrow][quad*8];
#pragma unroll
    for (int i=0;i<NT;i++) bfr[i] = *(const bf16x8*)&Bs[s][i*16 + mrow][quad*8];
#pragma unroll
    for (int mi=0;mi<4;mi++)
#pragma unroll
      for (int ni=0;ni<NT;ni++)
        acc[mi][ni] = __builtin_amdgcn_mfma_f32_16x16x32_bf16(af[mi], bfr[ni], acc[mi][ni], 0,0,0);
    if (it + 2 < nIter) issue((it+2) % 3);
  }

  // C/D layout: col = lane&15, row = quad*4 + reg  [m89/m91]
#pragma unroll
  for (int mi=0;mi<4;mi++)
#pragma unroll
    for (int ni=0;ni<NT;ni++) {
      const int col  = bn*NT*16 + ni*16 + mrow;
      const int row0 = bm*64 + mi*16 + quad*4;
#pragma unroll
      for (int r=0;r<4;r++)
        epi(row0 + r, col, bz, acc[mi][ni][r]);
    }
}

// ---------------------------------------------------------------------------
// Typed linear, wave-block NT=4, per-lane row gather in the DMA source.
// grid (x = m-tile 0..127, y = n-tile 0..15, z = type)
// ---------------------------------------------------------------------------
__global__ __launch_bounds__(64, 2)
void gemm_typed(const u16* __restrict__ A, const u16* __restrict__ B,
                const int* __restrict__ idx, const int* __restrict__ cnt,
                u16* __restrict__ node_in, u16* __restrict__ node_out)
{
  const int bz = blockIdx.z;
  const int count = cnt[bz];
  const int m0 = blockIdx.x << 6;
  if (m0 >= count) return;
  __shared__ __align__(16) u16 As[3][64][32];
  __shared__ __align__(16) u16 Bs[3][64][32];
  const int bn = blockIdx.y;
  const int lane = threadIdx.x;
  const int mrow = lane & 15;
  const int quad = lane >> 4;
  const int srow = lane >> 2;
  const int scol = (lane & 3) << 3;
  const int* myidx = idx + bz*8192;

  const u16* gA[4];
  const u16* gB[4];
#pragma unroll
  for (int i=0;i<4;i++){
    int r = m0 + i*16 + srow;
    if (r >= count) r = count - 1;
    gA[i] = A + (long)myidx[r]*512 + scol;
    gB[i] = B + (long)bz*1024*512 + (long)(bn*64 + i*16 + srow)*512 + scol;
  }

  floatx4 acc[4][4];
#pragma unroll
  for (int i=0;i<4;i++)
#pragma unroll
    for (int j=0;j<4;j++) acc[i][j] = 0.f;

  auto issue = [&](int s){
#pragma unroll
    for (int i=0;i<4;i++){ GLOAD16(&As[s][i*16+srow][scol], gA[i]); gA[i] += 32; }
#pragma unroll
    for (int i=0;i<4;i++){ GLOAD16(&Bs[s][i*16+srow][scol], gB[i]); gB[i] += 32; }
  };

  issue(0); issue(1);
  for (int it = 0; it < 16; ++it) {
    if (it < 15) asm volatile("s_waitcnt vmcnt(8)" ::: "memory");
    else         asm volatile("s_waitcnt vmcnt(0)" ::: "memory");
    const int s = it % 3;
    bf16x8 af[4], bfr[4];
#pragma unroll
    for (int i=0;i<4;i++) af[i]  = *(const bf16x8*)&As[s][i*16 + mrow][quad*8];
#pragma unroll
    for (int i=0;i<4;i++) bfr[i] = *(const bf16x8*)&Bs[s][i*16 + mrow][quad*8];
#pragma unroll
    for (int mi=0;mi<4;mi++)
#pragma unroll
      for (int ni=0;ni<4;ni++)
        acc[mi][ni] = __builtin_amdgcn_mfma_f32_16x16x32_bf16(af[mi], bfr[ni], acc[mi][ni], 0,0,0);
    if (it + 2 < 16) issue((it+2) % 3);
  }

#pragma unroll
  for (int mi=0;mi<4;mi++) {
    const int lr0 = mi*16 + quad*4;
#pragma unroll
    for (int r=0;r<4;r++) {
      const int lr = lr0 + r;
      if (m0 + lr >= count) continue;
      const long orig = myidx[m0 + lr];
#pragma unroll
      for (int ni=0;ni<4;ni++) {
        const int col = bn*64 + ni*16 + mrow;
        u16 h = f2bf(acc[mi][ni][r]);
        if (col < 512) node_in [orig*512 + col]       = h;
        else           node_out[orig*512 + (col-512)] = h;
      }
    }
  }
}

// --- epilogues --------------------------------------------------------------
struct EpiPV {      // bz in [0,16): batch = bz&7, in/out = bz>>3
  const float* il; u16* X;
  __device__ void operator()(int row, int col, int bz, float v) const {
    long gr = (long)(bz & 7)*1024 + row;
    int colOff = 512 + ((bz >> 3) << 9);
    X[gr*2048 + colOff + col] = f2bf(v * il[(long)(bz>>3)*8192 + gr]);
  }
};
struct EpiG1 {      // col<512: rn -> X[:,1536+col]; else z -> zbuf (bf16)
  const u16* nodes; const u16* b_r; const u16* b_z; u16* X; u16* zbuf;
  __device__ void operator()(int row, int col, int bz, float v) const {
    if (col < 512) {
      float r = sigm(v + bf2f(b_r[col]));
      X[(long)row*2048 + 1536 + col] = f2bf(r * bf2f(nodes[(long)row*512 + col]));
    } else {
      int c = col - 512;
      zbuf[(long)row*512 + c] = f2bf(sigm(v + bf2f(b_z[c])));
    }
  }
};
struct EpiG2 {      // h_hat = tanh(v + b_t) = 2*sigm(2t)-1; out = (1-z)n + z h_hat
  const u16* zbuf; const u16* nodes; const u16* b_t; const int* flags; void* out;
  __device__ void operator()(int row, int col, int bz, float v) const {
    long idx = (long)row*512 + col;
    float t = fminf(fmaxf(v + bf2f(b_t[col]), -15.f), 15.f);
    float h = 2.f*sigm(2.f*t) - 1.f;
    float z = bf2f(zbuf[idx]);
    float nv = bf2f(nodes[idx]);
    float o2 = (1.f - z)*nv + z*h;
    if (flags[0]) ((float*)out)[idx] = o2;
    else          ((u16*)out)[idx]   = f2bf(o2);
  }
};

// --- merged weight transposes: 9 slices ------------------------------------
struct TrDesc {
  const u16* src[9]; u16* dst[9]; int rot[9]; int ldD[9]; int rows[9]; int modK[9];
};
__global__ __launch_bounds__(256)
void k_wtrans(TrDesc d)
{
  __shared__ u16 tile[32][33];
  const int z = blockIdx.z;
  const int r0 = blockIdx.y*32;
  if (r0 >= d.rows[z]) return;
  const u16* src = d.src[z];
  u16* dst = d.dst[z];
  const int c0 = blockIdx.x*32;
  const int tx = threadIdx.x, ty = threadIdx.y;
#pragma unroll
  for (int i=0;i<32;i+=8)
    tile[ty+i][tx] = src[(long)(r0+ty+i)*512 + c0 + tx];
  __syncthreads();
  const int k0 = (r0 + d.rot[z]) % d.modK[z];
#pragma unroll
  for (int i=0;i<32;i+=8)
    dst[(long)(c0+ty+i)*d.ldD[z] + k0 + tx] = tile[tx][ty+i];
}

// --- merged V transposes ---------------------------------------------------
__global__ __launch_bounds__(256)
void k_vtrans(const u16* __restrict__ nin, const u16* __restrict__ nout,
              u16* __restrict__ vin, u16* __restrict__ vout)
{
  __shared__ u16 tile[32][33];
  const int z = blockIdx.z;
  const int b = z & 7;
  const u16* src = (z < 8 ? nin : nout) + (long)b*1024*512;
  u16* dst = (z < 8 ? vin : vout) + (long)b*512*1024;
  const int c0 = blockIdx.x*32, r0 = blockIdx.y*32;
  const int tx = threadIdx.x, ty = threadIdx.y;
#pragma unroll
  for (int i=0;i<32;i+=8)
    tile[ty+i][tx] = src[(long)(r0+ty+i)*512 + c0 + tx];
  __syncthreads();
#pragma unroll
  for (int i=0;i<32;i+=8)
    dst[(long)(c0+ty+i)*1024 + r0 + tx] = tile[tx][ty+i];
}

__device__ __forceinline__ void load8f(float* f, const u16* p){
  uint4 q = *(const uint4*)p;
  unsigned w[4] = {q.x, q.y, q.z, q.w};
#pragma unroll
  for (int i=0;i<4;i++){ f[2*i] = bf2f((u16)(w[i]&0xffffu)); f[2*i+1] = bf2f((u16)(w[i]>>16)); }
}

// --- per-row scalar projections --------------------------------------------
__global__ __launch_bounds__(256)
void k_svec(const u16* __restrict__ nodes, const u16* __restrict__ nin, const u16* __restrict__ nout,
            const u16* __restrict__ aiq, const u16* __restrict__ aiv,
            const u16* __restrict__ aoq, const u16* __restrict__ aov,
            float* sq_all, float* sv_all)
{
  const int lane = threadIdx.x & 63, wave = threadIdx.x >> 6;
  const long row = (long)blockIdx.x*4 + wave;
  const int c = lane << 3;
  float xn[8], xi[8], xo[8], q1[8], v1[8], q2[8], v2[8];
  load8f(xn, nodes + row*512 + c);
  load8f(xi, nin   + row*512 + c);
  load8f(xo, nout  + row*512 + c);
  load8f(q1, aiq + c); load8f(v1, aiv + c);
  load8f(q2, aoq + c); load8f(v2, aov + c);
  float s0=0,s1=0,s2=0,s3=0;
#pragma unroll
  for (int j=0;j<8;j++){ s0 += xn[j]*q1[j]; s1 += xn[j]*q2[j]; s2 += xi[j]*v1[j]; s3 += xo[j]*v2[j]; }
#pragma unroll
  for (int off=32; off; off>>=1){
    s0 += __shfl_xor(s0, off);
    s1 += __shfl_xor(s1, off);
    s2 += __shfl_xor(s2, off);
    s3 += __shfl_xor(s3, off);
  }
  if (lane==0){
    sq_all[row] = s0; sq_all[8192 + row] = s1;
    sv_all[row] = s2; sv_all[8192 + row] = s3;
  }
}

// --- masked-softmax stats + materialize P (bf16); y selects in/out ---------
__global__ __launch_bounds__(256)
void k_stats(const int* __restrict__ mask, const float* __restrict__ sq_all,
             const float* __restrict__ sv_all, u16* __restrict__ P, float* __restrict__ il_all)
{
  const int lane = threadIdx.x & 63, wave = threadIdx.x >> 6;
  const long row = (long)blockIdx.x*4 + wave;           // within 8192
  const long gr  = (long)blockIdx.y*8192 + row;         // global (in/out)
  const int* mrow = mask + gr*1024;
  const float* svb = sv_all + (long)blockIdx.y*8192 + (row >> 10)*1024;
  const float qs = sq_all[gr];
  float m = -3.0e38f;
  float e[4][4];
#pragma unroll
  for (int it=0; it<4; ++it) {
    int j = it*256 + lane*4;
    int4 mk = *(const int4*)&mrow[j];
    float4 s = *(const float4*)&svb[j];
    e[it][0] = mk.x > 0 ? lrelu(qs + s.x) : -1e9f;
    e[it][1] = mk.y > 0 ? lrelu(qs + s.y) : -1e9f;
    e[it][2] = mk.z > 0 ? lrelu(qs + s.z) : -1e9f;
    e[it][3] = mk.w > 0 ? lrelu(qs + s.w) : -1e9f;
    m = fmaxf(m, fmaxf(fmaxf(e[it][0], e[it][1]), fmaxf(e[it][2], e[it][3])));
  }
#pragma unroll
  for (int off=32; off; off>>=1) m = fmaxf(m, __shfl_xor(m, off));
  float l = 0.f;
#pragma unroll
  for (int it=0; it<4; ++it) {
    int j = it*256 + lane*4;
    float p0 = __expf(e[it][0] - m), p1 = __expf(e[it][1] - m);
    float p2 = __expf(e[it][2] - m), p3 = __expf(e[it][3] - m);
    ushort4 pk;
    pk.x = f2bf(p0); pk.y = f2bf(p1); pk.z = f2bf(p2); pk.w = f2bf(p3);
    *(ushort4*)&P[gr*1024 + j] = pk;
    l += (p0 + p1) + (p2 + p3);
  }
#pragma unroll
  for (int off=32; off; off>>=1) l += __shfl_xor(l, off);
  if (lane==0) il_all[gr] = 1.f / l;
}

// ---------------------------------------------------------------------------
extern "C" void kernel_launch(void* const* d_in, const int* in_sizes, int n_in,
                              void* d_out, int out_size, void* d_ws, size_t ws_size,
                              hipStream_t stream)
{
  const void* nodes_r = d_in[0];
  const int*  mask    = (const int*)d_in[1];
  const int*  ntype   = (const int*)d_in[2];

  char* base = (char*)d_ws;
  size_t o = 0;
  auto alloc = [&](size_t bytes){ void* p = base + o; o += (bytes + 255) & ~size_t(255); return p; };
  int*  flags   = (int*)alloc(256);
  int*  cnt     = (int*)alloc(256);
  int*  idx     = (int*)alloc(3ll*8192*4);
  u16* cn_nodes = (u16*)alloc(8192ll*512*2);
  u16* cn_Win   = (u16*)alloc(3ll*512*512*2);
  u16* cn_Wout  = (u16*)alloc(3ll*512*512*2);
  u16* cn_Wr    = (u16*)alloc(1536ll*512*2);
  u16* cn_Wz    = (u16*)alloc(1536ll*512*2);
  u16* cn_Wt    = (u16*)alloc(1536ll*512*2);
  u16* cn_aiq   = (u16*)alloc(512*2);
  u16* cn_aiv   = (u16*)alloc(512*2);
  u16* cn_aoq   = (u16*)alloc(512*2);
  u16* cn_aov   = (u16*)alloc(512*2);
  u16* cn_br    = (u16*)alloc(512*2);
  u16* cn_bz    = (u16*)alloc(512*2);
  u16* cn_bt    = (u16*)alloc(512*2);
  u16* node_in  = (u16*)alloc(8192ll*512*2);   // zbuf aliases this after svec
  u16* node_out = (u16*)alloc(8192ll*512*2);   // adjacent (joint memset)
  u16* Vt       = (u16*)alloc(16ll*512*1024*2); // [in 8 | out 8] batches
  u16* X        = (u16*)alloc(8192ll*2048*2);   // [nodes|h_in|h_out|rn], ld 2048
  u16* P        = (u16*)alloc(16ll*1024*1024*2);// [in 8 | out 8] batches
  u16* Wio_t    = (u16*)alloc(3ll*1024*512*2);
  u16* Wrz_t    = (u16*)alloc(1024ll*1536*2);
  u16* Wt_t     = (u16*)alloc(512ll*1536*2);
  float* sq_all = (float*)alloc(16384*4);
  float* sv_all = (float*)alloc(16384*4);
  float* il_all = (float*)alloc(16384*4);
  u16* zbuf = node_in;   // alias: node_in last read by k_svec; zbuf written at G1

  hipMemsetAsync(node_in, 0, 2ll*8192*512*2, stream);   // node_in + node_out

  k_detect<<<1, 256, 0, stream>>>((const u16*)nodes_r, ntype, flags);

  // merged canon of 13 tensors (+ nodes into X)
  CanonDesc cd;
  const int canonN[13] = {8192*512, 3*512*512, 3*512*512, 1536*512, 1536*512, 1536*512,
                          512,512,512,512,512,512,512};
  u16* canonDst[13] = {cn_nodes, cn_Win, cn_Wout, cn_Wr, cn_Wz, cn_Wt,
                       cn_aiq, cn_aiv, cn_aoq, cn_aov, cn_br, cn_bz, cn_bt};
  const int canonSrcIdx[13] = {0,3,4,9,11,13,5,6,7,8,10,12,14};
  int blk = 0;
  for (int s=0;s<13;s++){
    cd.src[s] = d_in[canonSrcIdx[s]];
    cd.dst[s] = canonDst[s];
    cd.n4[s]  = canonN[s]/4;
    cd.startBlk[s] = blk;
    blk += (cd.n4[s] + 255)/256;
  }
  k_canon_all<<<blk, 256, 0, stream>>>(cd, X, flags);

  k_build_idx<<<1, 256, 0, stream>>>(ntype, flags, idx, cnt);

  // merged weight transposes
  TrDesc td;
  td.src[0]=cn_Wr; td.src[1]=cn_Wz; td.src[2]=cn_Wt;
  td.dst[0]=Wrz_t; td.dst[1]=Wrz_t + 512ll*1536; td.dst[2]=Wt_t;
  td.rot[0]=512; td.rot[1]=512; td.rot[2]=0;
  td.ldD[0]=1536; td.ldD[1]=1536; td.ldD[2]=1536;
  td.rows[0]=1536; td.rows[1]=1536; td.rows[2]=1536;
  td.modK[0]=1536; td.modK[1]=1536; td.modK[2]=1536;
  for (int t=0;t<3;t++){
    td.src[3+t]=cn_Win  + (long)t*512*512; td.dst[3+t]=Wio_t + (long)t*1024*512;
    td.src[6+t]=cn_Wout + (long)t*512*512; td.dst[6+t]=Wio_t + (long)t*1024*512 + 512ll*512;
    td.rot[3+t]=td.rot[6+t]=0; td.ldD[3+t]=td.ldD[6+t]=512;
    td.rows[3+t]=td.rows[6+t]=512; td.modK[3+t]=td.modK[6+t]=512;
  }
  k_wtrans<<<dim3(16,48,9), dim3(32,8), 0, stream>>>(td);

  // typed linear, gathered rows (wave blocks, 64x64 tiles)
  gemm_typed<<<dim3(128,16,3), 64, 0, stream>>>(cn_nodes, Wio_t, idx, cnt, node_in, node_out);

  // V^T for PV B-operands
  k_vtrans<<<dim3(16,32,16), dim3(32,8), 0, stream>>>(node_in, node_out, Vt, Vt + 8ll*512*1024);

  k_svec<<<2048, 256, 0, stream>>>(cn_nodes, node_in, node_out, cn_aiq, cn_aiv, cn_aoq, cn_aov,
                                   sq_all, sv_all);

  // merged stats (in + out)
  k_stats<<<dim3(2048,2), 256, 0, stream>>>(mask, sq_all, sv_all, P, il_all);

  // merged PV GEMMs (MODE 1, 64x128 tiles): 16 x 4 x 16 = 1024 waves
  gemm_w64<1,8><<<dim3(16,4,16), 64, 0, stream>>>(P, 1024, 1024ll*1024, Vt, 1024, 512ll*1024, 1024,
                                                  EpiPV{il_all, X});

  // GGNN G1 (64x128 tiles): 128 x 8 = 1024 waves
  gemm_w64<0,8><<<dim3(128,8,1), 64, 0, stream>>>(X, 2048, 0ll, Wrz_t, 1536, 0ll, 1536,
                                                  EpiG1{cn_nodes, cn_br, cn_bz, X, zbuf});
  // GGNN G2 (64x64 tiles): 128 x 8 = 1024 waves
  gemm_w64<0,4><<<dim3(128,8,1), 64, 0, stream>>>(X + 512, 2048, 0ll, Wt_t, 1536, 0ll, 1536,
                                                  EpiG2{zbuf, cn_nodes, cn_bt, flags, (void*)d_out});
}

// Round 8
// 379.257 us; speedup vs baseline: 1.3388x; 1.3388x over previous
//
#include <hip/hip_runtime.h>
#include <hip/hip_bf16.h>
#include <stdint.h>

typedef unsigned short u16;
typedef __attribute__((ext_vector_type(8))) short bf16x8;
typedef __attribute__((ext_vector_type(4))) float floatx4;

__device__ __forceinline__ float bf2f(u16 v){ return __uint_as_float(((unsigned)v)<<16); }
__device__ __forceinline__ u16 f2bf(float f){
  unsigned u = __float_as_uint(f);
  unsigned r = 0x7fffu + ((u>>16)&1u);
  return (u16)((u+r)>>16);
}
__device__ __forceinline__ float lrelu(float x){ return x > 0.f ? x : 0.2f*x; }
__device__ __forceinline__ float sigm(float t){
  t = fminf(fmaxf(t, -30.f), 30.f);
  return 1.f/(1.f + __expf(-t));
}

#define GLOAD16(ldsdst, gsrc) \
  __builtin_amdgcn_global_load_lds((const __attribute__((address_space(1))) void*)(gsrc), \
      (__attribute__((address_space(3))) void*)(ldsdst), 16, 0, 0)

// ---------------------------------------------------------------------------
// dtype detector: flags[0]=1 -> float inputs are f32; flags[1]=1 -> node_type int64
// ---------------------------------------------------------------------------
__global__ void k_detect(const u16* __restrict__ nodes_raw,
                         const int* __restrict__ ntype_raw, int* flags)
{
  __shared__ int s_wild, s_nz;
  if (threadIdx.x == 0){ s_wild = 0; s_nz = 0; }
  __syncthreads();
  int wild = 0;
#pragma unroll
  for (int i = 0; i < 16; i++){
    u16 w = nodes_raw[threadIdx.x*16 + i];
    int e = (w >> 7) & 0xFF;
    if (e != 0 && (e < 102 || e > 152)) wild++;
  }
  int nz = 0;
  if (threadIdx.x < 255 && ntype_raw[2*threadIdx.x + 1] != 0) nz = 1;
  atomicAdd(&s_wild, wild);
  atomicAdd(&s_nz, nz);
  __syncthreads();
  if (threadIdx.x == 0){
    flags[0] = (s_wild > 1024) ? 1 : 0;
    flags[1] = (s_nz == 0) ? 1 : 0;
  }
}

// --- merged canonicalization of all 13 float tensors (+ nodes into X) ------
struct CanonDesc {
  const void* src[13];
  u16*        dst[13];
  int startBlk[13];
  int n4[13];
};
__global__ __launch_bounds__(256)
void k_canon_all(CanonDesc d, u16* __restrict__ X, const int* __restrict__ flags)
{
  int blk = blockIdx.x;
  int seg = 0;
#pragma unroll
  for (int s = 1; s < 13; s++) if (blk >= d.startBlk[s]) seg = s;
  int i = (blk - d.startBlk[seg])*256 + threadIdx.x;
  if (i >= d.n4[seg]) return;
  uint2 bits;
  if (flags[0]) {
    float4 v = ((const float4*)d.src[seg])[i];
    ushort4 o2;
    o2.x = f2bf(v.x); o2.y = f2bf(v.y); o2.z = f2bf(v.z); o2.w = f2bf(v.w);
    bits = *(uint2*)&o2;
  } else {
    bits = ((const uint2*)d.src[seg])[i];
  }
  ((uint2*)d.dst[seg])[i] = bits;
  if (seg == 0) {               // nodes also -> X[:,0:512), ld 2048
    int e0 = i*4;
    long r = e0 >> 9;
    int  c = e0 & 511;
    *(uint2*)&X[r*2048 + c] = bits;
  }
}

// --- per-type row index lists ----------------------------------------------
__global__ void k_build_idx(const int* __restrict__ ntype, const int* __restrict__ flags,
                            int* __restrict__ idx, int* __restrict__ cnt)
{
  __shared__ int c[3];
  if (threadIdx.x < 3) c[threadIdx.x] = 0;
  __syncthreads();
  const int i64 = flags[1];
  for (int i = threadIdx.x; i < 8192; i += 256){
    int t = i64 ? ntype[2*i] : ntype[i];
    if (t >= 2 && t <= 4){
      int p = atomicAdd(&c[t-2], 1);
      idx[(t-2)*8192 + p] = i;
    }
  }
  __syncthreads();
  if (threadIdx.x < 3) cnt[threadIdx.x] = c[threadIdx.x];
}

// ---------------------------------------------------------------------------
// 128x128 bf16 GEMM, BK=64 double-buffered (64 KB LDS = 2 blocks/CU, which
// equals the grid cap for every call site). Wall time = per-block K-loop
// latency, so halving the iteration count (vs BK=32) is the win.
// Safe ordering (R4 pattern): wait vmcnt(0) -> barrier -> issue other buf.
// MODE 0: bm=bx, bn=by, bz=bzi.   MODE 1: bz=bx, bn=by, bm=bzi.
// ---------------------------------------------------------------------------
template<int MODE, class Epi>
__global__ __launch_bounds__(256)
void gemm_bt(const u16* __restrict__ A, int ldA, long sAz,
             const u16* __restrict__ B, int ldB, long sBz,
             int K, Epi epi)
{
  __shared__ __align__(16) u16 As[2][128][64];
  __shared__ __align__(16) u16 Bs[2][128][64];
  int bm, bn, bz;
  if (MODE == 0){ bm = blockIdx.x; bn = blockIdx.y; bz = blockIdx.z; }
  else          { bz = blockIdx.x; bn = blockIdx.y; bm = blockIdx.z; }
  const int tid  = threadIdx.x;
  const int lane = tid & 63;
  const int wave = tid >> 6;
  const int wm = (wave & 1) << 6;
  const int wn = (wave >> 1) << 6;
  const int mrow = lane & 15;
  const int quad = lane >> 4;

  const u16* Ab = A + (long)bz*sAz + (long)bm*128*ldA;
  const u16* Bb = B + (long)bz*sBz + (long)bn*128*ldB;
  const int srow = tid >> 3;           // 0..31
  const int scol = (tid & 7) << 3;     // 0..56, 8 bf16 = 16B
  const u16* gA[4];
  const u16* gB[4];
#pragma unroll
  for (int i=0;i<4;i++){
    gA[i] = Ab + (long)(srow + 32*i)*ldA + scol;
    gB[i] = Bb + (long)(srow + 32*i)*ldB + scol;
  }

  floatx4 acc[4][4];
#pragma unroll
  for (int i=0;i<4;i++)
#pragma unroll
    for (int j=0;j<4;j++) acc[i][j] = 0.f;

  auto issue = [&](int buf){
#pragma unroll
    for (int i=0;i<4;i++){ GLOAD16(&As[buf][srow+32*i][scol], gA[i]); gA[i] += 64; }
#pragma unroll
    for (int i=0;i<4;i++){ GLOAD16(&Bs[buf][srow+32*i][scol], gB[i]); gB[i] += 64; }
  };

  issue(0);
  const int nIter = K >> 6;            // K % 64 == 0 at all call sites
  for (int it = 0; it < nIter; ++it) {
    const int cur = it & 1;
    asm volatile("s_waitcnt vmcnt(0)" ::: "memory");
    __syncthreads();
    if (it + 1 < nIter) issue(cur ^ 1);
#pragma unroll
    for (int k32 = 0; k32 < 2; ++k32) {
      bf16x8 af[4], bfr[4];
#pragma unroll
      for (int i=0;i<4;i++) af[i]  = *(const bf16x8*)&As[cur][wm + i*16 + mrow][k32*32 + quad*8];
#pragma unroll
      for (int i=0;i<4;i++) bfr[i] = *(const bf16x8*)&Bs[cur][wn + i*16 + mrow][k32*32 + quad*8];
#pragma unroll
      for (int mi=0;mi<4;mi++)
#pragma unroll
        for (int ni=0;ni<4;ni++)
          acc[mi][ni] = __builtin_amdgcn_mfma_f32_16x16x32_bf16(af[mi], bfr[ni], acc[mi][ni], 0,0,0);
    }
  }

  // C/D layout: col = lane&15, row = quad*4 + reg  [m89/m91]
#pragma unroll
  for (int mi=0;mi<4;mi++)
#pragma unroll
    for (int ni=0;ni<4;ni++) {
      const int col  = (bn<<7) + wn + ni*16 + mrow;
      const int row0 = (bm<<7) + wm + mi*16 + quad*4;
#pragma unroll
      for (int r=0;r<4;r++)
        epi(row0 + r, col, bz, acc[mi][ni][r]);
    }
}

// ---------------------------------------------------------------------------
// Typed linear with row gather (BK=64 dbuf; x=bm(64, early-return), y=bn, z=t)
// ---------------------------------------------------------------------------
__global__ __launch_bounds__(256)
void gemm_typed(const u16* __restrict__ A, const u16* __restrict__ B,
                const int* __restrict__ idx, const int* __restrict__ cnt,
                u16* __restrict__ node_in, u16* __restrict__ node_out)
{
  const int bz = blockIdx.z;
  const int count = cnt[bz];
  const int m0 = blockIdx.x << 7;
  if (m0 >= count) return;
  __shared__ __align__(16) u16 As[2][128][64];
  __shared__ __align__(16) u16 Bs[2][128][64];
  const int bn = blockIdx.y;
  const int tid  = threadIdx.x;
  const int lane = tid & 63;
  const int wave = tid >> 6;
  const int wm = (wave & 1) << 6;
  const int wn = (wave >> 1) << 6;
  const int mrow = lane & 15;
  const int quad = lane >> 4;
  const int srow = tid >> 3;
  const int scol = (tid & 7) << 3;
  const int* myidx = idx + bz*8192;

  const u16* gA[4];
  const u16* gB[4];
#pragma unroll
  for (int i=0;i<4;i++){
    int r = m0 + srow + 32*i;
    if (r >= count) r = count - 1;
    gA[i] = A + (long)myidx[r]*512 + scol;
    gB[i] = B + (long)bz*1024*512 + (long)(bn*128 + srow + 32*i)*512 + scol;
  }

  floatx4 acc[4][4];
#pragma unroll
  for (int i=0;i<4;i++)
#pragma unroll
    for (int j=0;j<4;j++) acc[i][j] = 0.f;

  auto issue = [&](int buf){
#pragma unroll
    for (int i=0;i<4;i++){ GLOAD16(&As[buf][srow+32*i][scol], gA[i]); gA[i] += 64; }
#pragma unroll
    for (int i=0;i<4;i++){ GLOAD16(&Bs[buf][srow+32*i][scol], gB[i]); gB[i] += 64; }
  };

  issue(0);
  for (int it = 0; it < 8; ++it) {     // K=512 -> 8 iters
    const int cur = it & 1;
    asm volatile("s_waitcnt vmcnt(0)" ::: "memory");
    __syncthreads();
    if (it + 1 < 8) issue(cur ^ 1);
#pragma unroll
    for (int k32 = 0; k32 < 2; ++k32) {
      bf16x8 af[4], bfr[4];
#pragma unroll
      for (int i=0;i<4;i++) af[i]  = *(const bf16x8*)&As[cur][wm + i*16 + mrow][k32*32 + quad*8];
#pragma unroll
      for (int i=0;i<4;i++) bfr[i] = *(const bf16x8*)&Bs[cur][wn + i*16 + mrow][k32*32 + quad*8];
#pragma unroll
      for (int mi=0;mi<4;mi++)
#pragma unroll
        for (int ni=0;ni<4;ni++)
          acc[mi][ni] = __builtin_amdgcn_mfma_f32_16x16x32_bf16(af[mi], bfr[ni], acc[mi][ni], 0,0,0);
    }
  }

#pragma unroll
  for (int mi=0;mi<4;mi++) {
    const int lr0 = wm + mi*16 + quad*4;
#pragma unroll
    for (int r=0;r<4;r++) {
      const int lr = lr0 + r;
      if (m0 + lr >= count) continue;
      const long orig = myidx[m0 + lr];
#pragma unroll
      for (int ni=0;ni<4;ni++) {
        const int col = (bn<<7) + wn + ni*16 + mrow;
        u16 h = f2bf(acc[mi][ni][r]);
        if (col < 512) node_in [orig*512 + col]       = h;
        else           node_out[orig*512 + (col-512)] = h;
      }
    }
  }
}

// --- epilogues --------------------------------------------------------------
struct EpiPV {      // bz in [0,16): batch = bz&7, in/out = bz>>3
  const float* il; u16* X;
  __device__ void operator()(int row, int col, int bz, float v) const {
    long gr = (long)(bz & 7)*1024 + row;
    int colOff = 512 + ((bz >> 3) << 9);
    X[gr*2048 + colOff + col] = f2bf(v * il[(long)(bz>>3)*8192 + gr]);
  }
};
struct EpiG1 {      // col<512: rn -> X[:,1536+col]; else z -> zbuf (bf16)
  const u16* nodes; const u16* b_r; const u16* b_z; u16* X; u16* zbuf;
  __device__ void operator()(int row, int col, int bz, float v) const {
    if (col < 512) {
      float r = sigm(v + bf2f(b_r[col]));
      X[(long)row*2048 + 1536 + col] = f2bf(r * bf2f(nodes[(long)row*512 + col]));
    } else {
      int c = col - 512;
      zbuf[(long)row*512 + c] = f2bf(sigm(v + bf2f(b_z[c])));
    }
  }
};
struct EpiG2 {      // h_hat = tanh(v + b_t) = 2*sigm(2t)-1; out = (1-z)n + z h_hat
  const u16* zbuf; const u16* nodes; const u16* b_t; const int* flags; void* out;
  __device__ void operator()(int row, int col, int bz, float v) const {
    long idx = (long)row*512 + col;
    float t = fminf(fmaxf(v + bf2f(b_t[col]), -15.f), 15.f);
    float h = 2.f*sigm(2.f*t) - 1.f;
    float z = bf2f(zbuf[idx]);
    float nv = bf2f(nodes[idx]);
    float o2 = (1.f - z)*nv + z*h;
    if (flags[0]) ((float*)out)[idx] = o2;
    else          ((u16*)out)[idx]   = f2bf(o2);
  }
};

// --- merged weight transposes: 9 slices ------------------------------------
struct TrDesc {
  const u16* src[9]; u16* dst[9]; int rot[9]; int ldD[9]; int rows[9]; int modK[9];
};
__global__ __launch_bounds__(256)
void k_wtrans(TrDesc d)
{
  __shared__ u16 tile[32][33];
  const int z = blockIdx.z;
  const int r0 = blockIdx.y*32;
  if (r0 >= d.rows[z]) return;
  const u16* src = d.src[z];
  u16* dst = d.dst[z];
  const int c0 = blockIdx.x*32;
  const int tx = threadIdx.x, ty = threadIdx.y;
#pragma unroll
  for (int i=0;i<32;i+=8)
    tile[ty+i][tx] = src[(long)(r0+ty+i)*512 + c0 + tx];
  __syncthreads();
  const int k0 = (r0 + d.rot[z]) % d.modK[z];
#pragma unroll
  for (int i=0;i<32;i+=8)
    dst[(long)(c0+ty+i)*d.ldD[z] + k0 + tx] = tile[tx][ty+i];
}

// --- merged V transposes ---------------------------------------------------
__global__ __launch_bounds__(256)
void k_vtrans(const u16* __restrict__ nin, const u16* __restrict__ nout,
              u16* __restrict__ vin, u16* __restrict__ vout)
{
  __shared__ u16 tile[32][33];
  const int z = blockIdx.z;
  const int b = z & 7;
  const u16* src = (z < 8 ? nin : nout) + (long)b*1024*512;
  u16* dst = (z < 8 ? vin : vout) + (long)b*512*1024;
  const int c0 = blockIdx.x*32, r0 = blockIdx.y*32;
  const int tx = threadIdx.x, ty = threadIdx.y;
#pragma unroll
  for (int i=0;i<32;i+=8)
    tile[ty+i][tx] = src[(long)(r0+ty+i)*512 + c0 + tx];
  __syncthreads();
#pragma unroll
  for (int i=0;i<32;i+=8)
    dst[(long)(c0+ty+i)*1024 + r0 + tx] = tile[tx][ty+i];
}

__device__ __forceinline__ void load8f(float* f, const u16* p){
  uint4 q = *(const uint4*)p;
  unsigned w[4] = {q.x, q.y, q.z, q.w};
#pragma unroll
  for (int i=0;i<4;i++){ f[2*i] = bf2f((u16)(w[i]&0xffffu)); f[2*i+1] = bf2f((u16)(w[i]>>16)); }
}

// --- per-row scalar projections --------------------------------------------
__global__ __launch_bounds__(256)
void k_svec(const u16* __restrict__ nodes, const u16* __restrict__ nin, const u16* __restrict__ nout,
            const u16* __restrict__ aiq, const u16* __restrict__ aiv,
            const u16* __restrict__ aoq, const u16* __restrict__ aov,
            float* sq_all, float* sv_all)
{
  const int lane = threadIdx.x & 63, wave = threadIdx.x >> 6;
  const long row = (long)blockIdx.x*4 + wave;
  const int c = lane << 3;
  float xn[8], xi[8], xo[8], q1[8], v1[8], q2[8], v2[8];
  load8f(xn, nodes + row*512 + c);
  load8f(xi, nin   + row*512 + c);
  load8f(xo, nout  + row*512 + c);
  load8f(q1, aiq + c); load8f(v1, aiv + c);
  load8f(q2, aoq + c); load8f(v2, aov + c);
  float s0=0,s1=0,s2=0,s3=0;
#pragma unroll
  for (int j=0;j<8;j++){ s0 += xn[j]*q1[j]; s1 += xn[j]*q2[j]; s2 += xi[j]*v1[j]; s3 += xo[j]*v2[j]; }
#pragma unroll
  for (int off=32; off; off>>=1){
    s0 += __shfl_xor(s0, off);
    s1 += __shfl_xor(s1, off);
    s2 += __shfl_xor(s2, off);
    s3 += __shfl_xor(s3, off);
  }
  if (lane==0){
    sq_all[row] = s0; sq_all[8192 + row] = s1;
    sv_all[row] = s2; sv_all[8192 + row] = s3;
  }
}

// --- masked-softmax stats + materialize P (bf16); y selects in/out ---------
__global__ __launch_bounds__(256)
void k_stats(const int* __restrict__ mask, const float* __restrict__ sq_all,
             const float* __restrict__ sv_all, u16* __restrict__ P, float* __restrict__ il_all)
{
  const int lane = threadIdx.x & 63, wave = threadIdx.x >> 6;
  const long row = (long)blockIdx.x*4 + wave;           // within 8192
  const long gr  = (long)blockIdx.y*8192 + row;         // global (in/out)
  const int* mrow = mask + gr*1024;
  const float* svb = sv_all + (long)blockIdx.y*8192 + (row >> 10)*1024;
  const float qs = sq_all[gr];
  float m = -3.0e38f;
  float e[4][4];
#pragma unroll
  for (int it=0; it<4; ++it) {
    int j = it*256 + lane*4;
    int4 mk = *(const int4*)&mrow[j];
    float4 s = *(const float4*)&svb[j];
    e[it][0] = mk.x > 0 ? lrelu(qs + s.x) : -1e9f;
    e[it][1] = mk.y > 0 ? lrelu(qs + s.y) : -1e9f;
    e[it][2] = mk.z > 0 ? lrelu(qs + s.z) : -1e9f;
    e[it][3] = mk.w > 0 ? lrelu(qs + s.w) : -1e9f;
    m = fmaxf(m, fmaxf(fmaxf(e[it][0], e[it][1]), fmaxf(e[it][2], e[it][3])));
  }
#pragma unroll
  for (int off=32; off; off>>=1) m = fmaxf(m, __shfl_xor(m, off));
  float l = 0.f;
#pragma unroll
  for (int it=0; it<4; ++it) {
    int j = it*256 + lane*4;
    float p0 = __expf(e[it][0] - m), p1 = __expf(e[it][1] - m);
    float p2 = __expf(e[it][2] - m), p3 = __expf(e[it][3] - m);
    ushort4 pk;
    pk.x = f2bf(p0); pk.y = f2bf(p1); pk.z = f2bf(p2); pk.w = f2bf(p3);
    *(ushort4*)&P[gr*1024 + j] = pk;
    l += (p0 + p1) + (p2 + p3);
  }
#pragma unroll
  for (int off=32; off; off>>=1) l += __shfl_xor(l, off);
  if (lane==0) il_all[gr] = 1.f / l;
}

// ---------------------------------------------------------------------------
extern "C" void kernel_launch(void* const* d_in, const int* in_sizes, int n_in,
                              void* d_out, int out_size, void* d_ws, size_t ws_size,
                              hipStream_t stream)
{
  const void* nodes_r = d_in[0];
  const int*  mask    = (const int*)d_in[1];
  const int*  ntype   = (const int*)d_in[2];

  char* base = (char*)d_ws;
  size_t o = 0;
  auto alloc = [&](size_t bytes){ void* p = base + o; o += (bytes + 255) & ~size_t(255); return p; };
  int*  flags   = (int*)alloc(256);
  int*  cnt     = (int*)alloc(256);
  int*  idx     = (int*)alloc(3ll*8192*4);
  u16* cn_nodes = (u16*)alloc(8192ll*512*2);
  u16* cn_Win   = (u16*)alloc(3ll*512*512*2);
  u16* cn_Wout  = (u16*)alloc(3ll*512*512*2);
  u16* cn_Wr    = (u16*)alloc(1536ll*512*2);
  u16* cn_Wz    = (u16*)alloc(1536ll*512*2);
  u16* cn_Wt    = (u16*)alloc(1536ll*512*2);
  u16* cn_aiq   = (u16*)alloc(512*2);
  u16* cn_aiv   = (u16*)alloc(512*2);
  u16* cn_aoq   = (u16*)alloc(512*2);
  u16* cn_aov   = (u16*)alloc(512*2);
  u16* cn_br    = (u16*)alloc(512*2);
  u16* cn_bz    = (u16*)alloc(512*2);
  u16* cn_bt    = (u16*)alloc(512*2);
  u16* node_in  = (u16*)alloc(8192ll*512*2);   // zbuf aliases this after svec
  u16* node_out = (u16*)alloc(8192ll*512*2);   // adjacent (joint memset)
  u16* Vt       = (u16*)alloc(16ll*512*1024*2); // [in 8 | out 8] batches
  u16* X        = (u16*)alloc(8192ll*2048*2);   // [nodes|h_in|h_out|rn], ld 2048
  u16* P        = (u16*)alloc(16ll*1024*1024*2);// [in 8 | out 8] batches
  u16* Wio_t    = (u16*)alloc(3ll*1024*512*2);
  u16* Wrz_t    = (u16*)alloc(1024ll*1536*2);
  u16* Wt_t     = (u16*)alloc(512ll*1536*2);
  float* sq_all = (float*)alloc(16384*4);
  float* sv_all = (float*)alloc(16384*4);
  float* il_all = (float*)alloc(16384*4);
  u16* zbuf = node_in;   // alias: node_in last read by k_svec; zbuf written at G1

  hipMemsetAsync(node_in, 0, 2ll*8192*512*2, stream);   // node_in + node_out

  k_detect<<<1, 256, 0, stream>>>((const u16*)nodes_r, ntype, flags);

  // merged canon of 13 tensors (+ nodes into X)
  CanonDesc cd;
  const int canonN[13] = {8192*512, 3*512*512, 3*512*512, 1536*512, 1536*512, 1536*512,
                          512,512,512,512,512,512,512};
  u16* canonDst[13] = {cn_nodes, cn_Win, cn_Wout, cn_Wr, cn_Wz, cn_Wt,
                       cn_aiq, cn_aiv, cn_aoq, cn_aov, cn_br, cn_bz, cn_bt};
  const int canonSrcIdx[13] = {0,3,4,9,11,13,5,6,7,8,10,12,14};
  int blk = 0;
  for (int s=0;s<13;s++){
    cd.src[s] = d_in[canonSrcIdx[s]];
    cd.dst[s] = canonDst[s];
    cd.n4[s]  = canonN[s]/4;
    cd.startBlk[s] = blk;
    blk += (cd.n4[s] + 255)/256;
  }
  k_canon_all<<<blk, 256, 0, stream>>>(cd, X, flags);

  k_build_idx<<<1, 256, 0, stream>>>(ntype, flags, idx, cnt);

  // merged weight transposes
  TrDesc td;
  td.src[0]=cn_Wr; td.src[1]=cn_Wz; td.src[2]=cn_Wt;
  td.dst[0]=Wrz_t; td.dst[1]=Wrz_t + 512ll*1536; td.dst[2]=Wt_t;
  td.rot[0]=512; td.rot[1]=512; td.rot[2]=0;
  td.ldD[0]=1536; td.ldD[1]=1536; td.ldD[2]=1536;
  td.rows[0]=1536; td.rows[1]=1536; td.rows[2]=1536;
  td.modK[0]=1536; td.modK[1]=1536; td.modK[2]=1536;
  for (int t=0;t<3;t++){
    td.src[3+t]=cn_Win  + (long)t*512*512; td.dst[3+t]=Wio_t + (long)t*1024*512;
    td.src[6+t]=cn_Wout + (long)t*512*512; td.dst[6+t]=Wio_t + (long)t*1024*512 + 512ll*512;
    td.rot[3+t]=td.rot[6+t]=0; td.ldD[3+t]=td.ldD[6+t]=512;
    td.rows[3+t]=td.rows[6+t]=512; td.modK[3+t]=td.modK[6+t]=512;
  }
  k_wtrans<<<dim3(16,48,9), dim3(32,8), 0, stream>>>(td);

  // typed linear, gathered rows (BK=64)
  gemm_typed<<<dim3(64,8,3), 256, 0, stream>>>(cn_nodes, Wio_t, idx, cnt, node_in, node_out);

  // V^T for PV B-operands
  k_vtrans<<<dim3(16,32,16), dim3(32,8), 0, stream>>>(node_in, node_out, Vt, Vt + 8ll*512*1024);

  k_svec<<<2048, 256, 0, stream>>>(cn_nodes, node_in, node_out, cn_aiq, cn_aiv, cn_aoq, cn_aov,
                                   sq_all, sv_all);

  // merged stats (in + out)
  k_stats<<<dim3(2048,2), 256, 0, stream>>>(mask, sq_all, sv_all, P, il_all);

  // merged PV GEMMs (MODE 1): bz 0..15 = (in/out | batch), writes X[:,512:1536)
  gemm_bt<1><<<dim3(16,4,8), 256, 0, stream>>>(P, 1024, 1024ll*1024, Vt, 1024, 512ll*1024, 1024,
                                               EpiPV{il_all, X});

  // GGNN G1: [nodes|h_in|h_out] @ [W_r|W_z] (k-rotated) -> rn into X[:,1536:2048), z
  gemm_bt<0><<<dim3(64,8,1), 256, 0, stream>>>(X, 2048, 0ll, Wrz_t, 1536, 0ll, 1536,
                                               EpiG1{cn_nodes, cn_br, cn_bz, X, zbuf});
  // GGNN G2: [h_in|h_out|rn] @ W_t -> gated output
  gemm_bt<0><<<dim3(64,4,1), 256, 0, stream>>>(X + 512, 2048, 0ll, Wt_t, 1536, 0ll, 1536,
                                               EpiG2{zbuf, cn_nodes, cn_bt, flags, (void*)d_out});
}

// Round 9
// 353.029 us; speedup vs baseline: 1.4382x; 1.0743x over previous
//
#include <hip/hip_runtime.h>
#include <hip/hip_bf16.h>
#include <stdint.h>

typedef unsigned short u16;
typedef __attribute__((ext_vector_type(8))) short bf16x8;
typedef __attribute__((ext_vector_type(4))) float floatx4;

__device__ __forceinline__ float bf2f(u16 v){ return __uint_as_float(((unsigned)v)<<16); }
__device__ __forceinline__ u16 f2bf(float f){
  unsigned u = __float_as_uint(f);
  unsigned r = 0x7fffu + ((u>>16)&1u);
  return (u16)((u+r)>>16);
}
__device__ __forceinline__ float lrelu(float x){ return x > 0.f ? x : 0.2f*x; }
__device__ __forceinline__ float sigm(float t){
  t = fminf(fmaxf(t, -30.f), 30.f);
  return 1.f/(1.f + __expf(-t));
}

#define GLOAD16(ldsdst, gsrc) \
  __builtin_amdgcn_global_load_lds((const __attribute__((address_space(1))) void*)(gsrc), \
      (__attribute__((address_space(3))) void*)(ldsdst), 16, 0, 0)

// Swizzled LDS slot for 16B chunk (r,q) of a [rows][32] bf16 tile:
// slot = r*4 + (q ^ ((r>>1)&3)); spreads quad-group reads over all 8 bank
// groups (2-way = free) instead of 8-way conflicts of the linear layout.
__device__ __forceinline__ int swz(int r, int q){ return r*4 + (q ^ ((r>>1)&3)); }

// ---------------------------------------------------------------------------
// dtype detector: flags[0]=1 -> float inputs are f32; flags[1]=1 -> node_type int64
// ---------------------------------------------------------------------------
__global__ void k_detect(const u16* __restrict__ nodes_raw,
                         const int* __restrict__ ntype_raw, int* flags)
{
  __shared__ int s_wild, s_nz;
  if (threadIdx.x == 0){ s_wild = 0; s_nz = 0; }
  __syncthreads();
  int wild = 0;
#pragma unroll
  for (int i = 0; i < 16; i++){
    u16 w = nodes_raw[threadIdx.x*16 + i];
    int e = (w >> 7) & 0xFF;
    if (e != 0 && (e < 102 || e > 152)) wild++;
  }
  int nz = 0;
  if (threadIdx.x < 255 && ntype_raw[2*threadIdx.x + 1] != 0) nz = 1;
  atomicAdd(&s_wild, wild);
  atomicAdd(&s_nz, nz);
  __syncthreads();
  if (threadIdx.x == 0){
    flags[0] = (s_wild > 1024) ? 1 : 0;
    flags[1] = (s_nz == 0) ? 1 : 0;
  }
}

// --- merged canonicalization of all 13 float tensors (+ nodes into X) ------
struct CanonDesc {
  const void* src[13];
  u16*        dst[13];
  int startBlk[13];
  int n4[13];
};
__global__ __launch_bounds__(256)
void k_canon_all(CanonDesc d, u16* __restrict__ X, const int* __restrict__ flags)
{
  int blk = blockIdx.x;
  int seg = 0;
#pragma unroll
  for (int s = 1; s < 13; s++) if (blk >= d.startBlk[s]) seg = s;
  int i = (blk - d.startBlk[seg])*256 + threadIdx.x;
  if (i >= d.n4[seg]) return;
  uint2 bits;
  if (flags[0]) {
    float4 v = ((const float4*)d.src[seg])[i];
    ushort4 o2;
    o2.x = f2bf(v.x); o2.y = f2bf(v.y); o2.z = f2bf(v.z); o2.w = f2bf(v.w);
    bits = *(uint2*)&o2;
  } else {
    bits = ((const uint2*)d.src[seg])[i];
  }
  ((uint2*)d.dst[seg])[i] = bits;
  if (seg == 0) {               // nodes also -> X[:,0:512), ld 2048
    int e0 = i*4;
    long r = e0 >> 9;
    int  c = e0 & 511;
    *(uint2*)&X[r*2048 + c] = bits;
  }
}

// --- per-type row index lists ----------------------------------------------
__global__ void k_build_idx(const int* __restrict__ ntype, const int* __restrict__ flags,
                            int* __restrict__ idx, int* __restrict__ cnt)
{
  __shared__ int c[3];
  if (threadIdx.x < 3) c[threadIdx.x] = 0;
  __syncthreads();
  const int i64 = flags[1];
  for (int i = threadIdx.x; i < 8192; i += 256){
    int t = i64 ? ntype[2*i] : ntype[i];
    if (t >= 2 && t <= 4){
      int p = atomicAdd(&c[t-2], 1);
      idx[(t-2)*8192 + p] = i;
    }
  }
  __syncthreads();
  if (threadIdx.x < 3) cnt[threadIdx.x] = c[threadIdx.x];
}

// ---------------------------------------------------------------------------
// 128xBN bf16 GEMM, BK=32 double-buffered, XOR-swizzled LDS (conflict-free
// ds_read_b128). NBI = B staging instructions (2 -> BN=128, 1 -> BN=64).
// MODE 0: bm=bx, bn=by, bz=bzi.   MODE 1: bz=bx, bn=by, bm=bzi.
// ---------------------------------------------------------------------------
template<int MODE, int NBI, class Epi>
__global__ __launch_bounds__(256)
void gemm_bt(const u16* __restrict__ A, int ldA, long sAz,
             const u16* __restrict__ B, int ldB, long sBz,
             int K, Epi epi)
{
  constexpr int BN = NBI*64;           // 128 or 64
  constexpr int NT = BN/32;            // per-wave n tiles: 4 or 2
  __shared__ __align__(16) u16 As[2][128*32];
  __shared__ __align__(16) u16 Bs[2][BN*32];
  int bm, bn, bz;
  if (MODE == 0){ bm = blockIdx.x; bn = blockIdx.y; bz = blockIdx.z; }
  else          { bz = blockIdx.x; bn = blockIdx.y; bm = blockIdx.z; }
  const int tid  = threadIdx.x;
  const int lane = tid & 63;
  const int wave = tid >> 6;
  const int wm = (wave & 1) << 6;
  const int wn = (wave >> 1) * (BN/2);
  const int mrow = lane & 15;
  const int quad = lane >> 4;

  const u16* Ab = A + (long)bz*sAz + (long)bm*128*ldA;
  const u16* Bb = B + (long)bz*sBz + (long)bn*BN*ldB;

  // staging: slot o = i*256 + tid; chunk (r,q) with q un-swizzled from o
  const int oA0 = tid, oA1 = 256 + tid;
  const int rA0 = oA0 >> 2, rA1 = oA1 >> 2;
  const u16* gA0 = Ab + (long)rA0*ldA + (((oA0&3) ^ ((rA0>>1)&3)) << 3);
  const u16* gA1 = Ab + (long)rA1*ldA + (((oA1&3) ^ ((rA1>>1)&3)) << 3);
  const u16* gB0 = Bb + (long)rA0*ldB + (((oA0&3) ^ ((rA0>>1)&3)) << 3);
  const u16* gB1 = (NBI == 2) ? Bb + (long)rA1*ldB + (((oA1&3) ^ ((rA1>>1)&3)) << 3) : nullptr;

  // per-lane fragment byte offsets (u16 units), K-independent
  int offA[4], offB[NT];
#pragma unroll
  for (int i=0;i<4;i++){ int r = wm + i*16 + mrow; offA[i] = swz(r, quad)*8; }
#pragma unroll
  for (int i=0;i<NT;i++){ int r = wn + i*16 + mrow; offB[i] = swz(r, quad)*8; }

  floatx4 acc[4][NT];
#pragma unroll
  for (int i=0;i<4;i++)
#pragma unroll
    for (int j=0;j<NT;j++) acc[i][j] = 0.f;

  auto issue = [&](int buf){
    GLOAD16(&As[buf][oA0*8], gA0); gA0 += 32;
    GLOAD16(&As[buf][oA1*8], gA1); gA1 += 32;
    GLOAD16(&Bs[buf][oA0*8], gB0); gB0 += 32;
    if (NBI == 2){ GLOAD16(&Bs[buf][oA1*8], gB1); gB1 += 32; }
  };

  issue(0);
  const int nIter = K >> 5;
  for (int it = 0; it < nIter; ++it) {
    const int cur = it & 1;
    asm volatile("s_waitcnt vmcnt(0)" ::: "memory");
    __syncthreads();
    if (it + 1 < nIter) issue(cur ^ 1);
    bf16x8 af[4], bfr[NT];
#pragma unroll
    for (int i=0;i<4;i++)  af[i]  = *(const bf16x8*)&As[cur][offA[i]];
#pragma unroll
    for (int i=0;i<NT;i++) bfr[i] = *(const bf16x8*)&Bs[cur][offB[i]];
#pragma unroll
    for (int mi=0;mi<4;mi++)
#pragma unroll
      for (int ni=0;ni<NT;ni++)
        acc[mi][ni] = __builtin_amdgcn_mfma_f32_16x16x32_bf16(af[mi], bfr[ni], acc[mi][ni], 0,0,0);
  }

  // C/D layout: col = lane&15, row = quad*4 + reg  [m89/m91]
#pragma unroll
  for (int mi=0;mi<4;mi++)
#pragma unroll
    for (int ni=0;ni<NT;ni++) {
      const int col  = bn*BN + wn + ni*16 + mrow;
      const int row0 = (bm<<7) + wm + mi*16 + quad*4;
#pragma unroll
      for (int r=0;r<4;r++)
        epi(row0 + r, col, bz, acc[mi][ni][r]);
    }
}

// ---------------------------------------------------------------------------
// Typed linear with row gather (BK=32 dbuf, swizzled; x=bm, y=bn, z=t)
// ---------------------------------------------------------------------------
__global__ __launch_bounds__(256)
void gemm_typed(const u16* __restrict__ A, const u16* __restrict__ B,
                const int* __restrict__ idx, const int* __restrict__ cnt,
                u16* __restrict__ node_in, u16* __restrict__ node_out)
{
  const int bz = blockIdx.z;
  const int count = cnt[bz];
  const int m0 = blockIdx.x << 7;
  if (m0 >= count) return;
  __shared__ __align__(16) u16 As[2][128*32];
  __shared__ __align__(16) u16 Bs[2][128*32];
  const int bn = blockIdx.y;
  const int tid  = threadIdx.x;
  const int lane = tid & 63;
  const int wave = tid >> 6;
  const int wm = (wave & 1) << 6;
  const int wn = (wave >> 1) << 6;
  const int mrow = lane & 15;
  const int quad = lane >> 4;
  const int* myidx = idx + bz*8192;

  const int oA0 = tid, oA1 = 256 + tid;
  const int rA0 = oA0 >> 2, rA1 = oA1 >> 2;
  int gr0 = m0 + rA0; if (gr0 >= count) gr0 = count - 1;
  int gr1 = m0 + rA1; if (gr1 >= count) gr1 = count - 1;
  const u16* gA0 = A + (long)myidx[gr0]*512 + (((oA0&3) ^ ((rA0>>1)&3)) << 3);
  const u16* gA1 = A + (long)myidx[gr1]*512 + (((oA1&3) ^ ((rA1>>1)&3)) << 3);
  const u16* Bb = B + (long)bz*1024*512 + (long)bn*128*512;
  const u16* gB0 = Bb + (long)rA0*512 + (((oA0&3) ^ ((rA0>>1)&3)) << 3);
  const u16* gB1 = Bb + (long)rA1*512 + (((oA1&3) ^ ((rA1>>1)&3)) << 3);

  int offA[4], offB[4];
#pragma unroll
  for (int i=0;i<4;i++){ int r = wm + i*16 + mrow; offA[i] = swz(r, quad)*8; }
#pragma unroll
  for (int i=0;i<4;i++){ int r = wn + i*16 + mrow; offB[i] = swz(r, quad)*8; }

  floatx4 acc[4][4];
#pragma unroll
  for (int i=0;i<4;i++)
#pragma unroll
    for (int j=0;j<4;j++) acc[i][j] = 0.f;

  auto issue = [&](int buf){
    GLOAD16(&As[buf][oA0*8], gA0); gA0 += 32;
    GLOAD16(&As[buf][oA1*8], gA1); gA1 += 32;
    GLOAD16(&Bs[buf][oA0*8], gB0); gB0 += 32;
    GLOAD16(&Bs[buf][oA1*8], gB1); gB1 += 32;
  };

  issue(0);
  for (int it = 0; it < 16; ++it) {
    const int cur = it & 1;
    asm volatile("s_waitcnt vmcnt(0)" ::: "memory");
    __syncthreads();
    if (it + 1 < 16) issue(cur ^ 1);
    bf16x8 af[4], bfr[4];
#pragma unroll
    for (int i=0;i<4;i++) af[i]  = *(const bf16x8*)&As[cur][offA[i]];
#pragma unroll
    for (int i=0;i<4;i++) bfr[i] = *(const bf16x8*)&Bs[cur][offB[i]];
#pragma unroll
    for (int mi=0;mi<4;mi++)
#pragma unroll
      for (int ni=0;ni<4;ni++)
        acc[mi][ni] = __builtin_amdgcn_mfma_f32_16x16x32_bf16(af[mi], bfr[ni], acc[mi][ni], 0,0,0);
  }

#pragma unroll
  for (int mi=0;mi<4;mi++) {
    const int lr0 = wm + mi*16 + quad*4;
#pragma unroll
    for (int r=0;r<4;r++) {
      const int lr = lr0 + r;
      if (m0 + lr >= count) continue;
      const long orig = myidx[m0 + lr];
#pragma unroll
      for (int ni=0;ni<4;ni++) {
        const int col = (bn<<7) + wn + ni*16 + mrow;
        u16 h = f2bf(acc[mi][ni][r]);
        if (col < 512) node_in [orig*512 + col]       = h;
        else           node_out[orig*512 + (col-512)] = h;
      }
    }
  }
}

// --- epilogues --------------------------------------------------------------
struct EpiPV {      // bz in [0,16): batch = bz&7, in/out = bz>>3
  const float* il; u16* X;
  __device__ void operator()(int row, int col, int bz, float v) const {
    long gr = (long)(bz & 7)*1024 + row;
    int colOff = 512 + ((bz >> 3) << 9);
    X[gr*2048 + colOff + col] = f2bf(v * il[(long)(bz>>3)*8192 + gr]);
  }
};
struct EpiG1 {      // col<512: rn -> X[:,1536+col]; else z -> zbuf (bf16)
  const u16* nodes; const u16* b_r; const u16* b_z; u16* X; u16* zbuf;
  __device__ void operator()(int row, int col, int bz, float v) const {
    if (col < 512) {
      float r = sigm(v + bf2f(b_r[col]));
      X[(long)row*2048 + 1536 + col] = f2bf(r * bf2f(nodes[(long)row*512 + col]));
    } else {
      int c = col - 512;
      zbuf[(long)row*512 + c] = f2bf(sigm(v + bf2f(b_z[c])));
    }
  }
};
struct EpiG2 {      // h_hat = tanh(v + b_t) = 2*sigm(2t)-1; out = (1-z)n + z h_hat
  const u16* zbuf; const u16* nodes; const u16* b_t; const int* flags; void* out;
  __device__ void operator()(int row, int col, int bz, float v) const {
    long idx = (long)row*512 + col;
    float t = fminf(fmaxf(v + bf2f(b_t[col]), -15.f), 15.f);
    float h = 2.f*sigm(2.f*t) - 1.f;
    float z = bf2f(zbuf[idx]);
    float nv = bf2f(nodes[idx]);
    float o2 = (1.f - z)*nv + z*h;
    if (flags[0]) ((float*)out)[idx] = o2;
    else          ((u16*)out)[idx]   = f2bf(o2);
  }
};

// --- merged weight transposes: 9 slices ------------------------------------
struct TrDesc {
  const u16* src[9]; u16* dst[9]; int rot[9]; int ldD[9]; int rows[9]; int modK[9];
};
__global__ __launch_bounds__(256)
void k_wtrans(TrDesc d)
{
  __shared__ u16 tile[32][33];
  const int z = blockIdx.z;
  const int r0 = blockIdx.y*32;
  if (r0 >= d.rows[z]) return;
  const u16* src = d.src[z];
  u16* dst = d.dst[z];
  const int c0 = blockIdx.x*32;
  const int tx = threadIdx.x, ty = threadIdx.y;
#pragma unroll
  for (int i=0;i<32;i+=8)
    tile[ty+i][tx] = src[(long)(r0+ty+i)*512 + c0 + tx];
  __syncthreads();
  const int k0 = (r0 + d.rot[z]) % d.modK[z];
#pragma unroll
  for (int i=0;i<32;i+=8)
    dst[(long)(c0+ty+i)*d.ldD[z] + k0 + tx] = tile[tx][ty+i];
}

// --- merged V transposes ---------------------------------------------------
__global__ __launch_bounds__(256)
void k_vtrans(const u16* __restrict__ nin, const u16* __restrict__ nout,
              u16* __restrict__ vin, u16* __restrict__ vout)
{
  __shared__ u16 tile[32][33];
  const int z = blockIdx.z;
  const int b = z & 7;
  const u16* src = (z < 8 ? nin : nout) + (long)b*1024*512;
  u16* dst = (z < 8 ? vin : vout) + (long)b*512*1024;
  const int c0 = blockIdx.x*32, r0 = blockIdx.y*32;
  const int tx = threadIdx.x, ty = threadIdx.y;
#pragma unroll
  for (int i=0;i<32;i+=8)
    tile[ty+i][tx] = src[(long)(r0+ty+i)*512 + c0 + tx];
  __syncthreads();
#pragma unroll
  for (int i=0;i<32;i+=8)
    dst[(long)(c0+ty+i)*1024 + r0 + tx] = tile[tx][ty+i];
}

__device__ __forceinline__ void load8f(float* f, const u16* p){
  uint4 q = *(const uint4*)p;
  unsigned w[4] = {q.x, q.y, q.z, q.w};
#pragma unroll
  for (int i=0;i<4;i++){ f[2*i] = bf2f((u16)(w[i]&0xffffu)); f[2*i+1] = bf2f((u16)(w[i]>>16)); }
}

// --- per-row scalar projections --------------------------------------------
__global__ __launch_bounds__(256)
void k_svec(const u16* __restrict__ nodes, const u16* __restrict__ nin, const u16* __restrict__ nout,
            const u16* __restrict__ aiq, const u16* __restrict__ aiv,
            const u16* __restrict__ aoq, const u16* __restrict__ aov,
            float* sq_all, float* sv_all)
{
  const int lane = threadIdx.x & 63, wave = threadIdx.x >> 6;
  const long row = (long)blockIdx.x*4 + wave;
  const int c = lane << 3;
  float xn[8], xi[8], xo[8], q1[8], v1[8], q2[8], v2[8];
  load8f(xn, nodes + row*512 + c);
  load8f(xi, nin   + row*512 + c);
  load8f(xo, nout  + row*512 + c);
  load8f(q1, aiq + c); load8f(v1, aiv + c);
  load8f(q2, aoq + c); load8f(v2, aov + c);
  float s0=0,s1=0,s2=0,s3=0;
#pragma unroll
  for (int j=0;j<8;j++){ s0 += xn[j]*q1[j]; s1 += xn[j]*q2[j]; s2 += xi[j]*v1[j]; s3 += xo[j]*v2[j]; }
#pragma unroll
  for (int off=32; off; off>>=1){
    s0 += __shfl_xor(s0, off);
    s1 += __shfl_xor(s1, off);
    s2 += __shfl_xor(s2, off);
    s3 += __shfl_xor(s3, off);
  }
  if (lane==0){
    sq_all[row] = s0; sq_all[8192 + row] = s1;
    sv_all[row] = s2; sv_all[8192 + row] = s3;
  }
}

// --- masked-softmax stats + materialize P (bf16); y selects in/out ---------
__global__ __launch_bounds__(256)
void k_stats(const int* __restrict__ mask, const float* __restrict__ sq_all,
             const float* __restrict__ sv_all, u16* __restrict__ P, float* __restrict__ il_all)
{
  const int lane = threadIdx.x & 63, wave = threadIdx.x >> 6;
  const long row = (long)blockIdx.x*4 + wave;           // within 8192
  const long gr  = (long)blockIdx.y*8192 + row;         // global (in/out)
  const int* mrow = mask + gr*1024;
  const float* svb = sv_all + (long)blockIdx.y*8192 + (row >> 10)*1024;
  const float qs = sq_all[gr];
  float m = -3.0e38f;
  float e[4][4];
#pragma unroll
  for (int it=0; it<4; ++it) {
    int j = it*256 + lane*4;
    int4 mk = *(const int4*)&mrow[j];
    float4 s = *(const float4*)&svb[j];
    e[it][0] = mk.x > 0 ? lrelu(qs + s.x) : -1e9f;
    e[it][1] = mk.y > 0 ? lrelu(qs + s.y) : -1e9f;
    e[it][2] = mk.z > 0 ? lrelu(qs + s.z) : -1e9f;
    e[it][3] = mk.w > 0 ? lrelu(qs + s.w) : -1e9f;
    m = fmaxf(m, fmaxf(fmaxf(e[it][0], e[it][1]), fmaxf(e[it][2], e[it][3])));
  }
#pragma unroll
  for (int off=32; off; off>>=1) m = fmaxf(m, __shfl_xor(m, off));
  float l = 0.f;
#pragma unroll
  for (int it=0; it<4; ++it) {
    int j = it*256 + lane*4;
    float p0 = __expf(e[it][0] - m), p1 = __expf(e[it][1] - m);
    float p2 = __expf(e[it][2] - m), p3 = __expf(e[it][3] - m);
    ushort4 pk;
    pk.x = f2bf(p0); pk.y = f2bf(p1); pk.z = f2bf(p2); pk.w = f2bf(p3);
    *(ushort4*)&P[gr*1024 + j] = pk;
    l += (p0 + p1) + (p2 + p3);
  }
#pragma unroll
  for (int off=32; off; off>>=1) l += __shfl_xor(l, off);
  if (lane==0) il_all[gr] = 1.f / l;
}

// ---------------------------------------------------------------------------
extern "C" void kernel_launch(void* const* d_in, const int* in_sizes, int n_in,
                              void* d_out, int out_size, void* d_ws, size_t ws_size,
                              hipStream_t stream)
{
  const void* nodes_r = d_in[0];
  const int*  mask    = (const int*)d_in[1];
  const int*  ntype   = (const int*)d_in[2];

  char* base = (char*)d_ws;
  size_t o = 0;
  auto alloc = [&](size_t bytes){ void* p = base + o; o += (bytes + 255) & ~size_t(255); return p; };
  int*  flags   = (int*)alloc(256);
  int*  cnt     = (int*)alloc(256);
  int*  idx     = (int*)alloc(3ll*8192*4);
  u16* cn_nodes = (u16*)alloc(8192ll*512*2);
  u16* cn_Win   = (u16*)alloc(3ll*512*512*2);
  u16* cn_Wout  = (u16*)alloc(3ll*512*512*2);
  u16* cn_Wr    = (u16*)alloc(1536ll*512*2);
  u16* cn_Wz    = (u16*)alloc(1536ll*512*2);
  u16* cn_Wt    = (u16*)alloc(1536ll*512*2);
  u16* cn_aiq   = (u16*)alloc(512*2);
  u16* cn_aiv   = (u16*)alloc(512*2);
  u16* cn_aoq   = (u16*)alloc(512*2);
  u16* cn_aov   = (u16*)alloc(512*2);
  u16* cn_br    = (u16*)alloc(512*2);
  u16* cn_bz    = (u16*)alloc(512*2);
  u16* cn_bt    = (u16*)alloc(512*2);
  u16* node_in  = (u16*)alloc(8192ll*512*2);   // zbuf aliases this after svec
  u16* node_out = (u16*)alloc(8192ll*512*2);   // adjacent (joint memset)
  u16* Vt       = (u16*)alloc(16ll*512*1024*2); // [in 8 | out 8] batches
  u16* X        = (u16*)alloc(8192ll*2048*2);   // [nodes|h_in|h_out|rn], ld 2048
  u16* P        = (u16*)alloc(16ll*1024*1024*2);// [in 8 | out 8] batches
  u16* Wio_t    = (u16*)alloc(3ll*1024*512*2);
  u16* Wrz_t    = (u16*)alloc(1024ll*1536*2);
  u16* Wt_t     = (u16*)alloc(512ll*1536*2);
  float* sq_all = (float*)alloc(16384*4);
  float* sv_all = (float*)alloc(16384*4);
  float* il_all = (float*)alloc(16384*4);
  u16* zbuf = node_in;   // alias: node_in last read by k_svec; zbuf written at G1

  hipMemsetAsync(node_in, 0, 2ll*8192*512*2, stream);   // node_in + node_out

  k_detect<<<1, 256, 0, stream>>>((const u16*)nodes_r, ntype, flags);

  // merged canon of 13 tensors (+ nodes into X)
  CanonDesc cd;
  const int canonN[13] = {8192*512, 3*512*512, 3*512*512, 1536*512, 1536*512, 1536*512,
                          512,512,512,512,512,512,512};
  u16* canonDst[13] = {cn_nodes, cn_Win, cn_Wout, cn_Wr, cn_Wz, cn_Wt,
                       cn_aiq, cn_aiv, cn_aoq, cn_aov, cn_br, cn_bz, cn_bt};
  const int canonSrcIdx[13] = {0,3,4,9,11,13,5,6,7,8,10,12,14};
  int blk = 0;
  for (int s=0;s<13;s++){
    cd.src[s] = d_in[canonSrcIdx[s]];
    cd.dst[s] = canonDst[s];
    cd.n4[s]  = canonN[s]/4;
    cd.startBlk[s] = blk;
    blk += (cd.n4[s] + 255)/256;
  }
  k_canon_all<<<blk, 256, 0, stream>>>(cd, X, flags);

  k_build_idx<<<1, 256, 0, stream>>>(ntype, flags, idx, cnt);

  // merged weight transposes
  TrDesc td;
  td.src[0]=cn_Wr; td.src[1]=cn_Wz; td.src[2]=cn_Wt;
  td.dst[0]=Wrz_t; td.dst[1]=Wrz_t + 512ll*1536; td.dst[2]=Wt_t;
  td.rot[0]=512; td.rot[1]=512; td.rot[2]=0;
  td.ldD[0]=1536; td.ldD[1]=1536; td.ldD[2]=1536;
  td.rows[0]=1536; td.rows[1]=1536; td.rows[2]=1536;
  td.modK[0]=1536; td.modK[1]=1536; td.modK[2]=1536;
  for (int t=0;t<3;t++){
    td.src[3+t]=cn_Win  + (long)t*512*512; td.dst[3+t]=Wio_t + (long)t*1024*512;
    td.src[6+t]=cn_Wout + (long)t*512*512; td.dst[6+t]=Wio_t + (long)t*1024*512 + 512ll*512;
    td.rot[3+t]=td.rot[6+t]=0; td.ldD[3+t]=td.ldD[6+t]=512;
    td.rows[3+t]=td.rows[6+t]=512; td.modK[3+t]=td.modK[6+t]=512;
  }
  k_wtrans<<<dim3(16,48,9), dim3(32,8), 0, stream>>>(td);

  // typed linear, gathered rows (BK=32, swizzled)
  gemm_typed<<<dim3(64,8,3), 256, 0, stream>>>(cn_nodes, Wio_t, idx, cnt, node_in, node_out);

  // V^T for PV B-operands
  k_vtrans<<<dim3(16,32,16), dim3(32,8), 0, stream>>>(node_in, node_out, Vt, Vt + 8ll*512*1024);

  k_svec<<<2048, 256, 0, stream>>>(cn_nodes, node_in, node_out, cn_aiq, cn_aiv, cn_aoq, cn_aov,
                                   sq_all, sv_all);

  // merged stats (in + out)
  k_stats<<<dim3(2048,2), 256, 0, stream>>>(mask, sq_all, sv_all, P, il_all);

  // merged PV GEMMs (MODE 1, BN=128): bz 0..15 = (in/out | batch)
  gemm_bt<1,2><<<dim3(16,4,8), 256, 0, stream>>>(P, 1024, 1024ll*1024, Vt, 1024, 512ll*1024, 1024,
                                                 EpiPV{il_all, X});

  // GGNN G1 (BN=128): [nodes|h_in|h_out] @ [W_r|W_z] -> rn into X[:,1536:2048), z
  gemm_bt<0,2><<<dim3(64,8,1), 256, 0, stream>>>(X, 2048, 0ll, Wrz_t, 1536, 0ll, 1536,
                                                 EpiG1{cn_nodes, cn_br, cn_bz, X, zbuf});
  // GGNN G2 (BN=64, 512 blocks): [h_in|h_out|rn] @ W_t -> gated output
  gemm_bt<0,1><<<dim3(64,8,1), 256, 0, stream>>>(X + 512, 2048, 0ll, Wt_t, 1536, 0ll, 1536,
                                                 EpiG2{zbuf, cn_nodes, cn_bt, flags, (void*)d_out});
}